// Round 7
// baseline (334.130 us; speedup 1.0000x reference)
//
#include <hip/hip_runtime.h>
#include <hip/hip_bf16.h>
#include <math.h>

#define B_DIM   4096
#define IN_DIM  4096
#define OUT_DIM 4096

typedef __attribute__((ext_vector_type(8))) short  short8;   // 8 x bf16 = 4 VGPRs
typedef __attribute__((ext_vector_type(4))) float  floatx4;  // MFMA 16x16 accum

__device__ __forceinline__ ushort f2bf(float f) {
    unsigned b = __float_as_uint(f);
    return (ushort)((b + 0x7fffu + ((b >> 16) & 1u)) >> 16);   // RNE
}

// ---- merged conversion: blocks 0..1023 -> x (bf16 + fp64 colsum atomics),
//      blocks 1024..2047 -> W (bf16 only). Block-uniform role, no divergence.
//      Each block: 16 rows x 1024-col slab, thread = 4 cols.
__global__ void cvt_both(const float* __restrict__ x, const float* __restrict__ W,
                         ushort* __restrict__ xb, ushort* __restrict__ wb,
                         double* __restrict__ xbar_sum) {
    const int  bid = blockIdx.x;
    const bool isx = bid < 1024;
    const int  lb  = isx ? bid : bid - 1024;
    const int  c0  = (lb & 3) * 1024 + threadIdx.x * 4;
    const int  r0  = (lb >> 2) * 16;
    const float* src = isx ? x  : W;
    ushort*      dst = isx ? xb : wb;
    double s0 = 0, s1 = 0, s2 = 0, s3 = 0;
#pragma unroll 4
    for (int r = 0; r < 16; ++r) {
        size_t off = (size_t)(r0 + r) * IN_DIM + c0;
        float4 v = *(const float4*)(src + off);
        ushort4 o;
        o.x = f2bf(v.x); o.y = f2bf(v.y); o.z = f2bf(v.z); o.w = f2bf(v.w);
        *(ushort4*)(dst + off) = o;
        if (isx) {
            s0 += (double)v.x; s1 += (double)v.y;
            s2 += (double)v.z; s3 += (double)v.w;
        }
    }
    if (isx) {
        double* p = xbar_sum + c0;
        atomicAdd(p + 0, s0); atomicAdd(p + 1, s1);
        atomicAdd(p + 2, s2); atomicAdd(p + 3, s3);
    }
}

// ---- means: idx[o] from dot(xbar, W[o,:]) + b[o]. 512 blocks x 8 rows.
//      xbar (32 KB) loaded ONCE per block into LDS (was: 32 KB re-read from L2
//      per row-block x 4096 = 128 MB). W rows re-read fp32 (LLC-warm after
//      cvt_both: x+W = 128 MB < 256 MB LLC).
__global__ void means_idx(const float* __restrict__ W, const float* __restrict__ bias,
                          const double* __restrict__ xbar_sum, int* __restrict__ idx) {
    __shared__ double xs[4096];
    __shared__ double red4[4];
#pragma unroll
    for (int j = 0; j < 16; ++j)
        xs[j * 256 + threadIdx.x] = xbar_sum[j * 256 + threadIdx.x];
    __syncthreads();
    const int o0 = blockIdx.x * 8;
    for (int rr = 0; rr < 8; ++rr) {
        const int o = o0 + rr;
        size_t base = (size_t)o * IN_DIM;
        double s = 0.0;
#pragma unroll
        for (int j = 0; j < 4; ++j) {
            int i = j * 1024 + threadIdx.x * 4;
            float4 v = *(const float4*)(W + base + i);
            s += (double)v.x * xs[i]     + (double)v.y * xs[i + 1]
               + (double)v.z * xs[i + 2] + (double)v.w * xs[i + 3];
        }
#pragma unroll
        for (int off = 32; off; off >>= 1) s += __shfl_down(s, off, 64);
        if ((threadIdx.x & 63) == 0) red4[threadIdx.x >> 6] = s;
        __syncthreads();
        if (threadIdx.x == 0) {
            double tot = red4[0] + red4[1] + red4[2] + red4[3];
            // fp32 mod semantics as in jnp (md==3.0f edge lands in else/sigmoid)
            float mf = (float)(tot * (1.0 / (double)B_DIM) + (double)bias[o]);
            float md = fmodf(mf, 3.0f);
            if (md < 0.0f) md += 3.0f;
            idx[o] = (int)md;
        }
        __syncthreads();   // red4 reuse
    }
}

// ---- bf16 MFMA GEMM: R1-proven structure (measured 131.5 us, MfmaUtil 45.9).
// 256x256 tile, BK=32, 4-deep counted-vmcnt ring, monolithic 32-MFMA block,
// single raw barrier per K-tile, setprio around MFMA cluster.
// (Phase-split variants R2/R3/R5/R6 all measured slower: 134-139 us. Keep this.)
__global__ void __launch_bounds__(512, 2) gemm_bt_act(
    const ushort* __restrict__ A,   // [M,K] bf16 bits (x)
    const ushort* __restrict__ Bt,  // [N,K] bf16 bits (W)
    const float*  __restrict__ bias,
    const int*    __restrict__ idx,
    float*        __restrict__ out) {
    __shared__ __align__(16) ushort lds[4][2][256 * 32];

    const int t    = threadIdx.x;
    const int w    = t >> 6;
    const int l    = t & 63;
    const int quad = l >> 4;
    const int lrow = l & 15;
    const int wm   = w >> 2;      // 0..1 -> M half
    const int wn   = w & 3;       // 0..3 -> N quarter

    // XCD-bijective swizzle: 256 wgs; each XCD owns a contiguous 4x8 tile region
    const int b   = blockIdx.x;
    const int xcd = b & 7;
    const int p   = b >> 3;                       // 0..31
    const int m0  = ((xcd >> 1) * 4 + (p >> 3)) * 256;
    const int n0  = ((xcd & 1) * 8 + (p & 7)) * 256;

    const int K = IN_DIM;

    // staging addresses: per-thread K-invariant element offsets
    size_t aoff[2], boff[2];
    int    ldso[2];
#pragma unroll
    for (int j = 0; j < 2; ++j) {
        int chunk = j * 512 + t;                  // 16B granule index 0..1023
        int r     = chunk >> 2;                   // tile row 0..255
        int kb    = (chunk & 3) ^ ((r >> 1) & 3); // pre-swizzled global granule
        aoff[j] = (size_t)(m0 + r) * K + kb * 8;
        boff[j] = (size_t)(n0 + r) * K + kb * 8;
        ldso[j] = chunk * 8;                      // ushort units (linear dest)
    }

    // fragment LDS byte offsets; (r>>1)&3 == (lrow>>1)&3 since base row %16==0
    const int kbsw  = (quad ^ ((lrow >> 1) & 3)) * 16;
    const int abase = (wm * 128 + lrow) * 64 + kbsw;   // + mi*1024
    const int bbase = (wn * 64 + lrow) * 64 + kbsw;    // + ni*1024

    floatx4 acc[8][4] = {};

    // prologue: stage tiles 0..2 (12 loads/thread in flight)
#pragma unroll
    for (int pt = 0; pt < 3; ++pt) {
        int ks = pt * 32;
#pragma unroll
        for (int j = 0; j < 2; ++j) {
            __builtin_amdgcn_global_load_lds(
                (__attribute__((address_space(1))) void*)(A + aoff[j] + ks),
                (__attribute__((address_space(3))) void*)(&lds[pt][0][ldso[j]]), 16, 0, 0);
            __builtin_amdgcn_global_load_lds(
                (__attribute__((address_space(1))) void*)(Bt + boff[j] + ks),
                (__attribute__((address_space(3))) void*)(&lds[pt][1][ldso[j]]), 16, 0, 0);
        }
    }

#pragma unroll 1
    for (int kt = 0; kt < 128; ++kt) {
        // drain through tile kt only (oldest); tiles kt+1,kt+2 stay in flight
        asm volatile("s_waitcnt vmcnt(8)" ::: "memory");
        __builtin_amdgcn_s_barrier();

        {   // stage tile kt+3 into slot (kt+3)&3 (wrap at tail: harmless reload)
            int nt   = (kt + 3) & 127;
            int slot = (kt + 3) & 3;
            int ks   = nt * 32;
#pragma unroll
            for (int j = 0; j < 2; ++j) {
                __builtin_amdgcn_global_load_lds(
                    (__attribute__((address_space(1))) void*)(A + aoff[j] + ks),
                    (__attribute__((address_space(3))) void*)(&lds[slot][0][ldso[j]]), 16, 0, 0);
                __builtin_amdgcn_global_load_lds(
                    (__attribute__((address_space(1))) void*)(Bt + boff[j] + ks),
                    (__attribute__((address_space(3))) void*)(&lds[slot][1][ldso[j]]), 16, 0, 0);
            }
        }

        const char* sa = (const char*)&lds[kt & 3][0][0];
        const char* sb = (const char*)&lds[kt & 3][1][0];
        short8 af[8], bf[4];
#pragma unroll
        for (int mi = 0; mi < 8; ++mi)
            af[mi] = *(const short8*)(sa + abase + mi * 1024);
#pragma unroll
        for (int ni = 0; ni < 4; ++ni)
            bf[ni] = *(const short8*)(sb + bbase + ni * 1024);

        __builtin_amdgcn_s_setprio(1);
#pragma unroll
        for (int mi = 0; mi < 8; ++mi)
#pragma unroll
            for (int ni = 0; ni < 4; ++ni)
                acc[mi][ni] = __builtin_amdgcn_mfma_f32_16x16x32_bf16(
                    af[mi], bf[ni], acc[mi][ni], 0, 0, 0);
        __builtin_amdgcn_s_setprio(0);
    }

    // epilogue: y = acc + bias[col]; branchless activation by idx[col]
    // C/D mapping: col = lane&15, row = quad*4 + reg
#pragma unroll
    for (int ni = 0; ni < 4; ++ni) {
        int   col     = n0 + wn * 64 + ni * 16 + lrow;
        int   id      = idx[col];
        float bv      = bias[col];
        float a       = (id == 1) ? -2.0f : -1.0f;
        bool  isrelu  = (id == 0);
        bool  istanh  = (id == 1);
#pragma unroll
        for (int mi = 0; mi < 8; ++mi) {
            int rowb = m0 + wm * 128 + mi * 16 + quad * 4;
#pragma unroll
            for (int r = 0; r < 4; ++r) {
                float y   = acc[mi][ni][r] + bv;
                float e   = __expf(a * y);                     // v_exp_f32 path
                float s   = __builtin_amdgcn_rcpf(1.0f + e);   // v_rcp_f32
                float act = istanh ? fmaf(2.0f, s, -1.0f) : s;
                float v   = isrelu ? fmaxf(y, 0.0f) : act;
                out[(size_t)(rowb + r) * OUT_DIM + col] = v;
            }
        }
    }
}

extern "C" void kernel_launch(void* const* d_in, const int* in_sizes, int n_in,
                              void* d_out, int out_size, void* d_ws, size_t ws_size,
                              hipStream_t stream) {
    const float* x = (const float*)d_in[0];
    const float* W = (const float*)d_in[1];
    const float* b = (const float*)d_in[2];
    float* out = (float*)d_out;

    char* ws = (char*)d_ws;
    ushort* xb   = (ushort*)(ws);                        // 32 MB
    ushort* wb   = (ushort*)(ws + 33554432);             // 32 MB
    double* xbar = (double*)(ws + 67108864);             // 32 KB (column sums)
    int*    idx  = (int*)   (ws + 67108864 + 32768);     // 16 KB

    hipMemsetAsync(xbar, 0, IN_DIM * sizeof(double), stream);
    cvt_both<<<2048, 256, 0, stream>>>(x, W, xb, wb, xbar);
    means_idx<<<512, 256, 0, stream>>>(W, b, xbar, idx);
    gemm_bt_act<<<256, 512, 0, stream>>>(xb, wb, b, idx, out);
}

// Round 8
// 313.519 us; speedup vs baseline: 1.0657x; 1.0657x over previous
//
#include <hip/hip_runtime.h>
#include <hip/hip_bf16.h>
#include <math.h>

#define B_DIM   4096
#define IN_DIM  4096
#define OUT_DIM 4096

typedef __attribute__((ext_vector_type(8))) short  short8;   // 8 x bf16 = 4 VGPRs
typedef __attribute__((ext_vector_type(4))) float  floatx4;  // MFMA 16x16 accum

__device__ __forceinline__ ushort f2bf(float f) {
    unsigned b = __float_as_uint(f);
    return (ushort)((b + 0x7fffu + ((b >> 16) & 1u)) >> 16);   // RNE
}

// ---- fused: x fp32 -> bf16  AND  fp64 column sums of x (device-scope atomics) ----
// grid (4, 256): bx -> 1024-col slab (4 cols/thread), by -> 16-row chunk.
// (Best-measured pre-kernel config: R2/R4/R6, rest ~172-176 us.)
__global__ void cvt_x_colsum(const float* __restrict__ x, ushort* __restrict__ xb,
                             double* __restrict__ xbar_sum) {
    int c0 = blockIdx.x * 1024 + threadIdx.x * 4;
    int r0 = blockIdx.y * 16;
    double s0 = 0, s1 = 0, s2 = 0, s3 = 0;
#pragma unroll 4
    for (int r = 0; r < 16; ++r) {
        size_t off = (size_t)(r0 + r) * IN_DIM + c0;
        float4 v = *(const float4*)(x + off);
        ushort4 o;
        o.x = f2bf(v.x); o.y = f2bf(v.y); o.z = f2bf(v.z); o.w = f2bf(v.w);
        *(ushort4*)(xb + off) = o;
        s0 += (double)v.x; s1 += (double)v.y; s2 += (double)v.z; s3 += (double)v.w;
    }
    double* p = xbar_sum + c0;
    atomicAdd(p + 0, s0); atomicAdd(p + 1, s1);
    atomicAdd(p + 2, s2); atomicAdd(p + 3, s3);
}

// ---- fused: W fp32 -> bf16  AND  means[o] = dot(xbar,W[o,:]) + b[o] -> idx[o] ----
__global__ void cvt_w_means(const float* __restrict__ W, const float* __restrict__ bias,
                            const double* __restrict__ xbar_sum, ushort* __restrict__ wb,
                            int* __restrict__ idx) {
    __shared__ double red4[4];
    int o = blockIdx.x;
    size_t base = (size_t)o * IN_DIM;
    double s = 0.0;
#pragma unroll
    for (int j = 0; j < 4; ++j) {
        int i = j * 1024 + threadIdx.x * 4;
        float4 v = *(const float4*)(W + base + i);
        ushort4 ob;
        ob.x = f2bf(v.x); ob.y = f2bf(v.y); ob.z = f2bf(v.z); ob.w = f2bf(v.w);
        *(ushort4*)(wb + base + i) = ob;
        double2 xv0 = *(const double2*)(xbar_sum + i);
        double2 xv1 = *(const double2*)(xbar_sum + i + 2);
        s += (double)v.x * xv0.x + (double)v.y * xv0.y
           + (double)v.z * xv1.x + (double)v.w * xv1.y;
    }
#pragma unroll
    for (int off = 32; off; off >>= 1) s += __shfl_down(s, off, 64);
    if ((threadIdx.x & 63) == 0) red4[threadIdx.x >> 6] = s;
    __syncthreads();
    if (threadIdx.x == 0) {
        double tot = red4[0] + red4[1] + red4[2] + red4[3];
        float mf = (float)(tot * (1.0 / (double)B_DIM) + (double)bias[o]);
        float md = fmodf(mf, 3.0f);
        if (md < 0.0f) md += 3.0f;
        idx[o] = (int)md;
    }
}

// ---- bf16 MFMA GEMM: R1 counted-vmcnt ring + REGISTER FRAGMENT DOUBLE-BUFFER.
// 256x256 tile, BK=32, 4-slot LDS ring, 8 waves (2M x 4N), acc[8][4].
// Per body kt: barrier; stage kt+3; vmcnt(8) [tile kt+1 landed; kt+2,kt+3 in
// flight -- never 0, tail wraps]; ds_read frags(kt+1) -> SPARE set; 32 MFMA on
// CURRENT set. MFMA(kt) has no dep on the new reads => no lgkmcnt(0) between
// them: the DS pipe (~1152 cy/tile/CU) drains UNDER the MFMA cluster
// (~1242 cy/tile/CU), converting the measured serial sum (~2466 cy/tile) into
// max. Unroll x2 with named X/Y frag sets (no runtime-indexed arrays).
// Ring safety (unchanged from R1): stage(kt+3) targets slot (kt-1)&3; its
// reads (frags(kt-1), issued body kt-2) were consumed by MFMA(kt-1) before
// any wave reached this body's barrier. Wrap staging keeps vmcnt constant;
// body 127's frag read of slot 0 is a harmless dead read (tile-0 reload data,
// landed under the same gate).
// Swizzle (64B rows, 4 x 16B granules): LDS granule pg holds logical
// pg ^ ((r>>1)&3); applied on the per-lane GLOBAL address (linear LDS dest);
// fragment address uses the same XOR. Verified 0 bank conflicts.
__global__ void __launch_bounds__(512, 2) gemm_bt_act(
    const ushort* __restrict__ A,   // [M,K] bf16 bits (x)
    const ushort* __restrict__ Bt,  // [N,K] bf16 bits (W)
    const float*  __restrict__ bias,
    const int*    __restrict__ idx,
    float*        __restrict__ out) {
    __shared__ __align__(16) ushort lds[4][2][256 * 32];

    const int t    = threadIdx.x;
    const int w    = t >> 6;
    const int l    = t & 63;
    const int quad = l >> 4;
    const int lrow = l & 15;
    const int wm   = w >> 2;      // 0..1 -> M half
    const int wn   = w & 3;       // 0..3 -> N quarter

    // XCD-bijective swizzle: 256 wgs; each XCD owns a contiguous 4x8 tile region
    const int b   = blockIdx.x;
    const int xcd = b & 7;
    const int p   = b >> 3;                       // 0..31
    const int m0  = ((xcd >> 1) * 4 + (p >> 3)) * 256;
    const int n0  = ((xcd & 1) * 8 + (p & 7)) * 256;

    const int K = IN_DIM;

    // staging addresses: per-thread K-invariant element offsets
    size_t aoff[2], boff[2];
    int    ldso[2];
#pragma unroll
    for (int j = 0; j < 2; ++j) {
        int chunk = j * 512 + t;                  // 16B granule index 0..1023
        int r     = chunk >> 2;                   // tile row 0..255
        int kb    = (chunk & 3) ^ ((r >> 1) & 3); // pre-swizzled global granule
        aoff[j] = (size_t)(m0 + r) * K + kb * 8;
        boff[j] = (size_t)(n0 + r) * K + kb * 8;
        ldso[j] = chunk * 8;                      // ushort units (linear dest)
    }

    // fragment LDS byte offsets; (r>>1)&3 == (lrow>>1)&3 since base row %16==0
    const int kbsw  = (quad ^ ((lrow >> 1) & 3)) * 16;
    const int abase = (wm * 128 + lrow) * 64 + kbsw;   // + mi*1024
    const int bbase = (wn * 64 + lrow) * 64 + kbsw;    // + ni*1024

    floatx4 acc[8][4] = {};
    short8 aX[8], bX[4], aY[8], bY[4];

#define STAGE3(kt)                                                               \
    {                                                                             \
        int nt   = (kt) & 127;                                                    \
        int slot = (kt) & 3;                                                      \
        int ks   = nt * 32;                                                       \
        _Pragma("unroll")                                                         \
        for (int j = 0; j < 2; ++j) {                                             \
            __builtin_amdgcn_global_load_lds(                                     \
                (__attribute__((address_space(1))) void*)(A + aoff[j] + ks),      \
                (__attribute__((address_space(3))) void*)(&lds[slot][0][ldso[j]]), 16, 0, 0); \
            __builtin_amdgcn_global_load_lds(                                     \
                (__attribute__((address_space(1))) void*)(Bt + boff[j] + ks),     \
                (__attribute__((address_space(3))) void*)(&lds[slot][1][ldso[j]]), 16, 0, 0); \
        }                                                                         \
    }

#define READF(slot, AN, BN)                                                      \
    {                                                                             \
        const char* sa = (const char*)&lds[slot][0][0];                           \
        const char* sb = (const char*)&lds[slot][1][0];                           \
        _Pragma("unroll")                                                         \
        for (int mi = 0; mi < 8; ++mi) AN[mi] = *(const short8*)(sa + abase + mi * 1024); \
        _Pragma("unroll")                                                         \
        for (int ni = 0; ni < 4; ++ni) BN[ni] = *(const short8*)(sb + bbase + ni * 1024); \
    }

#define GBODY(kt, AC, BC, AN, BN)                                                \
    {                                                                             \
        __builtin_amdgcn_s_barrier();                                             \
        STAGE3((kt) + 3);                                                         \
        asm volatile("s_waitcnt vmcnt(8)" ::: "memory");                          \
        READF(((kt) + 1) & 3, AN, BN);                                            \
        __builtin_amdgcn_s_setprio(1);                                            \
        _Pragma("unroll")                                                         \
        for (int mi = 0; mi < 8; ++mi)                                            \
            _Pragma("unroll")                                                     \
            for (int ni = 0; ni < 4; ++ni)                                        \
                acc[mi][ni] = __builtin_amdgcn_mfma_f32_16x16x32_bf16(            \
                    AC[mi], BC[ni], acc[mi][ni], 0, 0, 0);                        \
        __builtin_amdgcn_s_setprio(0);                                            \
    }

    // prologue: stage tiles 0..2; gate tile 0; read frags(0) -> X
    STAGE3(0); STAGE3(1); STAGE3(2);
    asm volatile("s_waitcnt vmcnt(8)" ::: "memory");
    __builtin_amdgcn_s_barrier();
    READF(0, aX, bX);

#pragma unroll 1
    for (int kt = 0; kt < 128; kt += 2) {
        GBODY(kt,     aX, bX, aY, bY);
        GBODY(kt + 1, aY, bY, aX, bX);
    }
#undef GBODY
#undef READF
#undef STAGE3

    // epilogue: y = acc + bias[col]; branchless activation by idx[col]
    // C/D mapping: col = lane&15, row = quad*4 + reg
#pragma unroll
    for (int ni = 0; ni < 4; ++ni) {
        int   col     = n0 + wn * 64 + ni * 16 + lrow;
        int   id      = idx[col];
        float bv      = bias[col];
        float a       = (id == 1) ? -2.0f : -1.0f;
        bool  isrelu  = (id == 0);
        bool  istanh  = (id == 1);
#pragma unroll
        for (int mi = 0; mi < 8; ++mi) {
            int rowb = m0 + wm * 128 + mi * 16 + quad * 4;
#pragma unroll
            for (int r = 0; r < 4; ++r) {
                float y   = acc[mi][ni][r] + bv;
                float e   = __expf(a * y);                     // v_exp_f32 path
                float s   = __builtin_amdgcn_rcpf(1.0f + e);   // v_rcp_f32
                float act = istanh ? fmaf(2.0f, s, -1.0f) : s;
                float v   = isrelu ? fmaxf(y, 0.0f) : act;
                out[(size_t)(rowb + r) * OUT_DIM + col] = v;
            }
        }
    }
}

extern "C" void kernel_launch(void* const* d_in, const int* in_sizes, int n_in,
                              void* d_out, int out_size, void* d_ws, size_t ws_size,
                              hipStream_t stream) {
    const float* x = (const float*)d_in[0];
    const float* W = (const float*)d_in[1];
    const float* b = (const float*)d_in[2];
    float* out = (float*)d_out;

    char* ws = (char*)d_ws;
    ushort* xb   = (ushort*)(ws);                        // 32 MB
    ushort* wb   = (ushort*)(ws + 33554432);             // 32 MB
    double* xbar = (double*)(ws + 67108864);             // 32 KB (column sums)
    int*    idx  = (int*)   (ws + 67108864 + 32768);     // 16 KB

    hipMemsetAsync(xbar, 0, IN_DIM * sizeof(double), stream);
    cvt_x_colsum<<<dim3(4, 256), 256, 0, stream>>>(x, xb, xbar);
    cvt_w_means<<<4096, 256, 0, stream>>>(W, b, xbar, wb, idx);
    gemm_bt_act<<<256, 512, 0, stream>>>(xb, wb, b, idx, out);
}